// Round 2
// baseline (2843.395 us; speedup 1.0000x reference)
//
#include <hip/hip_runtime.h>
#include <hip/hip_fp16.h>

typedef _Float16 h2 __attribute__((ext_vector_type(2)));
typedef _Float16 h8 __attribute__((ext_vector_type(8)));
typedef float f4 __attribute__((ext_vector_type(4)));

static constexpr int TT = 2048;
static constexpr int BB = 64;
static constexpr int II = 256;
static constexpr int HH = 256;
static constexpr int G3 = 768;   // 3*H

static __device__ __forceinline__ unsigned int pk2(float a, float b) {
    return __builtin_bit_cast(unsigned int, __builtin_amdgcn_cvt_pkrtz(a, b));
}

// ---------------------------------------------------------------------------
// Kernel 0: cast W_ih fp32 -> fp16 (tiny, one-time)
// ---------------------------------------------------------------------------
__global__ void cast_wih(const float* __restrict__ w, _Float16* __restrict__ o, int n) {
    int i = blockIdx.x * blockDim.x + threadIdx.x;
    if (i < n) o[i] = (_Float16)w[i];
}

// ---------------------------------------------------------------------------
// Kernel 1: gi = x @ W_ih^T + b_ih, stored fp16 [B*T][768]
// Per-wave 64x64 C tile, K=256, no LDS. MFMA f32_16x16x32_f16.
// A frag: lane holds row (l&15), k = (l>>4)*8 + j  (contiguous in x row-major)
// B frag: lane holds col (l&15) = W_ih row, same k  (contiguous in W_ih row-major)
// C/D:    col = lane&15, row = (lane>>4)*4 + reg   (m89-verified mapping)
// ---------------------------------------------------------------------------
__global__ void gi_gemm(const float* __restrict__ x, const _Float16* __restrict__ wih,
                        const float* __restrict__ bih, _Float16* __restrict__ gi) {
    const int lane = threadIdx.x & 63;
    const int wid  = threadIdx.x >> 6;
    const int gt   = blockIdx.x * 4 + wid;       // wave-tile id, n fastest
    const int nt   = gt % 12;
    const int mt   = gt / 12;
    const int m0   = mt * 64;
    const int n0   = nt * 64;
    const int lr   = lane & 15;
    const int kg   = (lane >> 4) * 8;

    f4 acc[4][4] = {};

    #pragma unroll
    for (int kk = 0; kk < 256; kk += 32) {
        h8 af[4];
        h8 bf[4];
        #pragma unroll
        for (int m = 0; m < 4; ++m) {
            const float* ap = x + (size_t)(m0 + m * 16 + lr) * 256 + kk + kg;
            f4 lo = *(const f4*)ap;
            f4 hi = *(const f4*)(ap + 4);
            uint4 uu;
            uu.x = pk2(lo.x, lo.y);
            uu.y = pk2(lo.z, lo.w);
            uu.z = pk2(hi.x, hi.y);
            uu.w = pk2(hi.z, hi.w);
            af[m] = __builtin_bit_cast(h8, uu);
        }
        #pragma unroll
        for (int n = 0; n < 4; ++n) {
            bf[n] = *(const h8*)(wih + (size_t)(n0 + n * 16 + lr) * 256 + kk + kg);
        }
        #pragma unroll
        for (int m = 0; m < 4; ++m) {
            #pragma unroll
            for (int n = 0; n < 4; ++n) {
                acc[m][n] = __builtin_amdgcn_mfma_f32_16x16x32_f16(af[m], bf[n], acc[m][n], 0, 0, 0);
            }
        }
    }

    const int rg = (lane >> 4) * 4;
    #pragma unroll
    for (int n = 0; n < 4; ++n) {
        const int col = n0 + n * 16 + lr;
        const float bv = bih[col];
        #pragma unroll
        for (int m = 0; m < 4; ++m) {
            #pragma unroll
            for (int r = 0; r < 4; ++r) {
                const int row = m0 + m * 16 + rg + r;
                gi[(size_t)row * G3 + col] = (_Float16)(acc[m][n][r] + bv);
            }
        }
    }
}

// ---------------------------------------------------------------------------
// Kernel 2: sequential GRU scan. One workgroup per batch element.
// 768 threads; thread tid owns W_hh row tid (256 fp16 packed into 128 VGPRs).
// Per step: gh[tid] = dot2(W_row, h) via LDS-broadcast h, exchange via LDS,
// threads 0..255 do the gate math and update h (fp32 master + fp16 packed).
// ---------------------------------------------------------------------------
__global__ __launch_bounds__(768, 3) void gru_scan(
        const _Float16* __restrict__ gi, const float* __restrict__ whh,
        const float* __restrict__ bhh, float* __restrict__ out) {
    __shared__ alignas(16) unsigned int hpk[128];  // h as packed f16x2
    __shared__ float ghl[768];                     // h-side gate pre-activations
    __shared__ float hf[256];                      // h master copy (fp32)

    const int b   = blockIdx.x;
    const int tid = threadIdx.x;

    // Load this thread's W_hh row, pack to fp16x2 in VGPRs.
    unsigned int wpk[128];
    {
        const f4* wrow = (const f4*)(whh + (size_t)tid * 256);
        #pragma unroll
        for (int i = 0; i < 64; ++i) {
            f4 w = wrow[i];
            wpk[2 * i]     = pk2(w.x, w.y);
            wpk[2 * i + 1] = pk2(w.z, w.w);
        }
    }
    const float bias = bhh[tid];

    if (tid < 128) hpk[tid] = 0u;
    if (tid < 256) hf[tid] = 0.f;

    const _Float16* gb = gi + (size_t)b * TT * G3;
    float gr = 0.f, gz = 0.f, gn = 0.f;
    if (tid < 256) {  // prefetch gi[t=0]
        gr = (float)gb[tid];
        gz = (float)gb[256 + tid];
        gn = (float)gb[512 + tid];
    }
    __syncthreads();

    for (int t = 0; t < TT; ++t) {
        // prefetch next step's gi while the dots run
        float pr = 0.f, pz = 0.f, pn = 0.f;
        if (tid < 256 && t + 1 < TT) {
            const _Float16* g2 = gb + (size_t)(t + 1) * G3;
            pr = (float)g2[tid];
            pz = (float)g2[256 + tid];
            pn = (float)g2[512 + tid];
        }

        // gh[tid] = W_hh[tid,:] . h  (fp16 dot2, fp32 accum, 4 chains)
        float a0 = 0.f, a1 = 0.f, a2 = 0.f, a3 = 0.f;
        #pragma unroll
        for (int i = 0; i < 32; ++i) {
            uint4 hv = *(const uint4*)&hpk[i * 4];
            a0 = __builtin_amdgcn_fdot2(__builtin_bit_cast(h2, wpk[4 * i + 0]),
                                        __builtin_bit_cast(h2, hv.x), a0, false);
            a1 = __builtin_amdgcn_fdot2(__builtin_bit_cast(h2, wpk[4 * i + 1]),
                                        __builtin_bit_cast(h2, hv.y), a1, false);
            a2 = __builtin_amdgcn_fdot2(__builtin_bit_cast(h2, wpk[4 * i + 2]),
                                        __builtin_bit_cast(h2, hv.z), a2, false);
            a3 = __builtin_amdgcn_fdot2(__builtin_bit_cast(h2, wpk[4 * i + 3]),
                                        __builtin_bit_cast(h2, hv.w), a3, false);
        }
        ghl[tid] = ((a0 + a1) + (a2 + a3)) + bias;
        __syncthreads();

        if (tid < 256) {
            const float xr = gr + ghl[tid];
            const float xz = gz + ghl[256 + tid];
            const float r = __builtin_amdgcn_rcpf(1.f + __expf(-xr));
            const float z = __builtin_amdgcn_rcpf(1.f + __expf(-xz));
            const float xn = gn + r * ghl[512 + tid];
            const float th = 1.f - 2.f * __builtin_amdgcn_rcpf(__expf(2.f * xn) + 1.f);
            const float h0 = hf[tid];
            const float hn = (1.f - z) * th + z * h0;
            hf[tid] = hn;
            ((_Float16*)hpk)[tid] = (_Float16)hn;
            gr = pr; gz = pz; gn = pn;
        }
        __syncthreads();
    }

    if (tid < 256) out[(size_t)b * HH + tid] = hf[tid];
}

// ---------------------------------------------------------------------------
extern "C" void kernel_launch(void* const* d_in, const int* in_sizes, int n_in,
                              void* d_out, int out_size, void* d_ws, size_t ws_size,
                              hipStream_t stream) {
    const float* x   = (const float*)d_in[0];
    const float* wih = (const float*)d_in[1];
    const float* whh = (const float*)d_in[2];
    const float* bih = (const float*)d_in[3];
    const float* bhh = (const float*)d_in[4];
    float* out = (float*)d_out;

    // workspace: [0, 384KB) W_ih fp16 ; [512KB, 512KB+192MB) gi fp16
    _Float16* wih_h = (_Float16*)d_ws;
    _Float16* gi    = (_Float16*)((char*)d_ws + 512 * 1024);

    cast_wih<<<768, 256, 0, stream>>>(wih, wih_h, G3 * II);
    gi_gemm<<<6144, 256, 0, stream>>>(x, wih_h, bih, gi);
    gru_scan<<<BB, 768, 0, stream>>>(gi, whh, bhh, out);
}